// Round 2
// baseline (1760.635 us; speedup 1.0000x reference)
//
#include <hip/hip_runtime.h>
#include <cstdint>

typedef __attribute__((ext_vector_type(8))) short short8;
typedef __attribute__((ext_vector_type(4))) float f32x4;
typedef unsigned short u16;

#define HD 1024      // hidden
#define BSZ 512      // batch
#define NL 2
#define TSTEPS 32
#define BM 64
#define BN 128
#define BK 64

__device__ __forceinline__ u16 f2bf(float x) {
  union { float f; uint32_t u; } v; v.f = x;
  uint32_t r = v.u + 0x7FFFu + ((v.u >> 16) & 1u);   // round-to-nearest-even
  return (u16)(r >> 16);
}
__device__ __forceinline__ float sigm(float x) { return 1.f / (1.f + __expf(-x)); }
__device__ __forceinline__ float tanhfast(float x) { return 1.f - 2.f / (__expf(2.f * x) + 1.f); }

// ---- pack W2[l][n'][k] bf16, n' gate-interleaved: n' = (j/16)*64 + gate*16 + (j%16)
__global__ void pack_w2(const float* __restrict__ Wih, const float* __restrict__ Whh,
                        u16* __restrict__ W2) {
  int idx = blockIdx.x * 256 + threadIdx.x;        // 2*4096*256 threads, 8 k's each
  int l   = idx >> 20;
  int rem = idx & 0xFFFFF;
  int np  = rem >> 8;                               // permuted row 0..4095
  int k   = (rem & 255) << 3;
  int gate = (np >> 4) & 3;
  int j    = ((np >> 6) << 4) | (np & 15);
  int n    = (gate << 10) | j;                      // original gate-major row
  const float* src = (k < HD) ? (Wih + ((size_t)(l * 4096 + n) << 10) + k)
                              : (Whh + ((size_t)(l * 4096 + n) << 10) + (k - HD));
  float4 a = reinterpret_cast<const float4*>(src)[0];
  float4 b = reinterpret_cast<const float4*>(src)[1];
  union { u16 s[8]; short8 v; } o;
  o.s[0]=f2bf(a.x); o.s[1]=f2bf(a.y); o.s[2]=f2bf(a.z); o.s[3]=f2bf(a.w);
  o.s[4]=f2bf(b.x); o.s[5]=f2bf(b.y); o.s[6]=f2bf(b.z); o.s[7]=f2bf(b.w);
  *reinterpret_cast<short8*>(W2 + (((size_t)l * 4096 + np) << 11) + k) = o.v;
}

// ---- to_h_W fp32 -> bf16, same [2048][1024] layout
__global__ void pack_thw(const float* __restrict__ thw, u16* __restrict__ dst) {
  int idx = blockIdx.x * 256 + threadIdx.x;        // 262144 threads
  size_t off = (size_t)idx << 3;
  float4 a = reinterpret_cast<const float4*>(thw + off)[0];
  float4 b = reinterpret_cast<const float4*>(thw + off)[1];
  union { u16 s[8]; short8 v; } o;
  o.s[0]=f2bf(a.x); o.s[1]=f2bf(a.y); o.s[2]=f2bf(a.z); o.s[3]=f2bf(a.w);
  o.s[4]=f2bf(b.x); o.s[5]=f2bf(b.y); o.s[6]=f2bf(b.z); o.s[7]=f2bf(b.w);
  *reinterpret_cast<short8*>(dst + off) = o.v;
}

// ---- z->bf16 | x0 = broadcast(init_emb) bf16 | bias2[l][n'] = b_ih+b_hh permuted
__global__ void pack_small(const float* __restrict__ z, const float* __restrict__ emb,
                           const float* __restrict__ bih, const float* __restrict__ bhh,
                           u16* __restrict__ zb, u16* __restrict__ xb,
                           float* __restrict__ bias2) {
  int idx = blockIdx.x * 256 + threadIdx.x;        // 139264 total
  if (idx < 65536) {
    size_t off = (size_t)idx << 3;
    float4 a = reinterpret_cast<const float4*>(z + off)[0];
    float4 b = reinterpret_cast<const float4*>(z + off)[1];
    union { u16 s[8]; short8 v; } o;
    o.s[0]=f2bf(a.x); o.s[1]=f2bf(a.y); o.s[2]=f2bf(a.z); o.s[3]=f2bf(a.w);
    o.s[4]=f2bf(b.x); o.s[5]=f2bf(b.y); o.s[6]=f2bf(b.z); o.s[7]=f2bf(b.w);
    *reinterpret_cast<short8*>(zb + off) = o.v;
  } else if (idx < 131072) {
    size_t off = (size_t)(idx - 65536) << 3;
    int k = (int)(off & 1023);
    float4 a = reinterpret_cast<const float4*>(emb + k)[0];
    float4 b = reinterpret_cast<const float4*>(emb + k)[1];
    union { u16 s[8]; short8 v; } o;
    o.s[0]=f2bf(a.x); o.s[1]=f2bf(a.y); o.s[2]=f2bf(a.z); o.s[3]=f2bf(a.w);
    o.s[4]=f2bf(b.x); o.s[5]=f2bf(b.y); o.s[6]=f2bf(b.z); o.s[7]=f2bf(b.w);
    *reinterpret_cast<short8*>(xb + off) = o.v;
  } else if (idx < 139264) {
    int q = idx - 131072;                          // 0..8191
    int l = q >> 12, np = q & 4095;
    int gate = (np >> 4) & 3;
    int j    = ((np >> 6) << 4) | (np & 15);
    int n    = (gate << 10) | j;
    bias2[(l << 12) + np] = bih[(l << 12) + n] + bhh[(l << 12) + n];
  }
}

// ---- fused GEMM + epilogue.
// C[M=512, N] = A[512, K]bf16 @ W[N, K]bf16^T   (W row-major [N][K], stride K)
// A is split: cols [0,1024) from A0, [1024,2048) from A1 (both [512][1024] bf16).
// EPI=0: init   — val=tanh(acc+to_h_b[n]); n<1024 -> layer0, else layer1; h=bf16(val), c=0
// EPI=1: cell   — gates in acc[mi][0..3] (gate-interleaved N); update c0,hb0
// EPI=2: cell+y — also write y fp32
template<int EPI>
__global__ __launch_bounds__(256)
void lstm_gemm(const u16* __restrict__ A0, const u16* __restrict__ A1,
               const u16* __restrict__ W, const float* __restrict__ bias,
               float* __restrict__ cb0, float* __restrict__ cb1,
               u16* __restrict__ hb0, u16* __restrict__ hb1,
               float* __restrict__ yout, int K)
{
  __shared__ u16 smem[2 * (BM * BK + BN * BK)];   // 2 x (8KB A + 16KB B) = 48 KB
  const int tid  = threadIdx.x;
  const int lane = tid & 63;
  const int wave = tid >> 6;
  const int wr = wave >> 1, wc = wave & 1;        // 2x2 wave grid: 32 rows x 64 cols each
  const int lr = lane & 15, lk = lane >> 4;
  const int m0 = blockIdx.y * BM;
  const int n0 = blockIdx.x * BN;

  f32x4 acc[2][4];
  #pragma unroll
  for (int a = 0; a < 2; ++a)
    #pragma unroll
    for (int b = 0; b < 4; ++b) acc[a][b] = (f32x4){0.f, 0.f, 0.f, 0.f};

  auto stage = [&](int buf, int kt) {
    const int k0 = kt * BK;
    u16* Ad = smem + buf * 12288;
    u16* Bd = smem + buf * 12288 + BM * BK;
    const u16* Aptr; int kk;
    if (k0 < 1024) { Aptr = A0; kk = k0; } else { Aptr = A1; kk = k0 - 1024; }
    #pragma unroll
    for (int i = 0; i < 2; ++i) {                  // A: 64x64 bf16, 512 x 16B chunks
      int f = i * 256 + tid;
      int r = f >> 3, c = (f & 7) << 3;
      const u16* g = Aptr + (((size_t)(m0 + r)) << 10) + kk + c;
      __builtin_amdgcn_global_load_lds((const __attribute__((address_space(1))) void*)g,
                                       (__attribute__((address_space(3))) void*)(Ad + f * 8),
                                       16, 0, 0);
    }
    #pragma unroll
    for (int i = 0; i < 4; ++i) {                  // B: 128x64 bf16, 1024 x 16B chunks
      int f = i * 256 + tid;
      int r = f >> 3, c = (f & 7) << 3;
      const u16* g = W + (size_t)(n0 + r) * K + k0 + c;
      __builtin_amdgcn_global_load_lds((const __attribute__((address_space(1))) void*)g,
                                       (__attribute__((address_space(3))) void*)(Bd + f * 8),
                                       16, 0, 0);
    }
  };

  stage(0, 0);
  asm volatile("s_waitcnt vmcnt(0)" ::: "memory");
  __syncthreads();

  const int NT = K / BK;
  int cur = 0;
  for (int kt = 0; kt < NT; ++kt) {
    if (kt + 1 < NT) stage(cur ^ 1, kt + 1);
    const u16* Asb = smem + cur * 12288;
    const u16* Bsb = smem + cur * 12288 + BM * BK;
    #pragma unroll
    for (int ks = 0; ks < 2; ++ks) {
      short8 af[2], bfr[4];
      #pragma unroll
      for (int mi = 0; mi < 2; ++mi)
        af[mi] = *reinterpret_cast<const short8*>(Asb + (wr * 32 + mi * 16 + lr) * 64 + ks * 32 + lk * 8);
      #pragma unroll
      for (int g = 0; g < 4; ++g)
        bfr[g] = *reinterpret_cast<const short8*>(Bsb + (wc * 64 + g * 16 + lr) * 64 + ks * 32 + lk * 8);
      #pragma unroll
      for (int mi = 0; mi < 2; ++mi)
        #pragma unroll
        for (int g = 0; g < 4; ++g)
          acc[mi][g] = __builtin_amdgcn_mfma_f32_16x16x32_bf16(af[mi], bfr[g], acc[mi][g], 0, 0, 0);
    }
    asm volatile("s_waitcnt vmcnt(0)" ::: "memory");
    __syncthreads();
    cur ^= 1;
  }

  if constexpr (EPI == 0) {
    #pragma unroll
    for (int g = 0; g < 4; ++g) {
      int n = n0 + wc * 64 + g * 16 + lr;          // plain column (no gate permute)
      float bn = bias[n];
      int lsel = n >> 10, j = n & 1023;
      float* cb = lsel ? cb1 : cb0;
      u16*   hb = lsel ? hb1 : hb0;
      #pragma unroll
      for (int mi = 0; mi < 2; ++mi)
        #pragma unroll
        for (int i = 0; i < 4; ++i) {
          int r = m0 + wr * 32 + mi * 16 + lk * 4 + i;
          size_t idx = ((size_t)r << 10) + j;
          hb[idx] = f2bf(tanhfast(acc[mi][g][i] + bn));
          cb[idx] = 0.f;
        }
    }
  } else {
    float bi = bias[n0 + wc * 64 +  0 + lr];
    float bf = bias[n0 + wc * 64 + 16 + lr];
    float bg = bias[n0 + wc * 64 + 32 + lr];
    float bo = bias[n0 + wc * 64 + 48 + lr];
    int j = (blockIdx.x * 2 + wc) * 16 + lr;       // hidden unit
    #pragma unroll
    for (int mi = 0; mi < 2; ++mi)
      #pragma unroll
      for (int i = 0; i < 4; ++i) {
        int r = m0 + wr * 32 + mi * 16 + lk * 4 + i;
        size_t idx = ((size_t)r << 10) + j;
        float ig = sigm(acc[mi][0][i] + bi);
        float fg = sigm(acc[mi][1][i] + bf);
        float gg = tanhfast(acc[mi][2][i] + bg);
        float og = sigm(acc[mi][3][i] + bo);
        float cn = fg * cb0[idx] + ig * gg;
        cb0[idx] = cn;
        float hn = og * tanhfast(cn);
        hb0[idx] = f2bf(hn);
        if constexpr (EPI == 2) yout[idx] = hn;
      }
  }
}

extern "C" void kernel_launch(void* const* d_in, const int* in_sizes, int n_in,
                              void* d_out, int out_size, void* d_ws, size_t ws_size,
                              hipStream_t stream) {
  const float* z   = (const float*)d_in[0];
  const float* thw = (const float*)d_in[1];
  const float* thb = (const float*)d_in[2];
  const float* emb = (const float*)d_in[3];
  const float* Wih = (const float*)d_in[4];
  const float* Whh = (const float*)d_in[5];
  const float* bih = (const float*)d_in[6];
  const float* bhh = (const float*)d_in[7];
  float* out = (float*)d_out;

  char* ws = (char*)d_ws;
  size_t off = 0;
  auto carve = [&](size_t bytes) { char* p = ws + off; off += (bytes + 255) & ~(size_t)255; return p; };
  u16* W2     = (u16*)carve((size_t)NL * 4096 * 2048 * 2);   // 33.5 MB, gate-interleaved
  u16* thwb   = (u16*)carve((size_t)2048 * 1024 * 2);        // 4 MB
  u16* zb     = (u16*)carve((size_t)BSZ * HD * 2);
  u16* xb     = (u16*)carve((size_t)BSZ * HD * 2);
  u16* h0b0   = (u16*)carve((size_t)BSZ * HD * 2);
  u16* h0b1   = (u16*)carve((size_t)BSZ * HD * 2);
  u16* h1b0   = (u16*)carve((size_t)BSZ * HD * 2);
  u16* h1b1   = (u16*)carve((size_t)BSZ * HD * 2);
  float* c0   = (float*)carve((size_t)BSZ * HD * 4);
  float* c1   = (float*)carve((size_t)BSZ * HD * 4);
  float* bias2 = (float*)carve((size_t)NL * 4096 * 4);
  if (off > ws_size) return;   // fail loudly rather than corrupt

  u16* h0b[2] = { h0b0, h0b1 };
  u16* h1b[2] = { h1b0, h1b1 };

  pack_w2   <<<8192, 256, 0, stream>>>(Wih, Whh, W2);
  pack_thw  <<<1024, 256, 0, stream>>>(thw, thwb);
  pack_small<<< 544, 256, 0, stream>>>(z, emb, bih, bhh, zb, xb, bias2);

  // h0 init: tanh(z @ to_h_W^T + to_h_b); also zeroes c0/c1
  lstm_gemm<0><<<dim3(16, 8), 256, 0, stream>>>(zb, zb, thwb, thb,
                                                c0, c1, h0b[0], h1b[0], nullptr, 1024);

  for (int t = 0; t < TSTEPS; ++t) {
    const u16* xs = (t == 0) ? xb : h1b[t & 1];
    // layer 0: gates = [x | h0_old] @ W2[0]^T; writes h0_new (ping-pong), c0
    lstm_gemm<1><<<dim3(32, 8), 256, 0, stream>>>(
        xs, h0b[t & 1], W2, bias2,
        c0, nullptr, h0b[(t + 1) & 1], nullptr, nullptr, 2048);
    // layer 1: gates = [h0_new | h1_old] @ W2[1]^T; writes h1_new, c1, y_t
    lstm_gemm<2><<<dim3(32, 8), 256, 0, stream>>>(
        h0b[(t + 1) & 1], h1b[t & 1], W2 + (size_t)4096 * 2048, bias2 + 4096,
        c1, nullptr, h1b[(t + 1) & 1], nullptr, out + (size_t)t * BSZ * HD, 2048);
  }
}

// Round 4
// 1314.123 us; speedup vs baseline: 1.3398x; 1.3398x over previous
//
#include <hip/hip_runtime.h>
#include <cstdint>

typedef __attribute__((ext_vector_type(8))) short short8;
typedef __attribute__((ext_vector_type(4))) float f32x4;
typedef unsigned short u16;

#define HD 1024      // hidden
#define BSZ 512      // batch
#define NL 2
#define TSTEPS 32
#define BM 64
#define BN 64
#define BK 64

__device__ __forceinline__ u16 f2bf(float x) {
  union { float f; uint32_t u; } v; v.f = x;
  uint32_t r = v.u + 0x7FFFu + ((v.u >> 16) & 1u);   // round-to-nearest-even
  return (u16)(r >> 16);
}
__device__ __forceinline__ float sigm(float x) { return 1.f / (1.f + __expf(-x)); }
__device__ __forceinline__ float tanhfast(float x) { return 1.f - 2.f / (__expf(2.f * x) + 1.f); }

// ---- pack W2[l][n'][k] bf16, n' gate-interleaved: n' = (j/16)*64 + gate*16 + (j%16)
__global__ void pack_w2(const float* __restrict__ Wih, const float* __restrict__ Whh,
                        u16* __restrict__ W2) {
  int idx = blockIdx.x * 256 + threadIdx.x;        // 2*4096*256 threads, 8 k's each
  int l   = idx >> 20;
  int rem = idx & 0xFFFFF;
  int np  = rem >> 8;                               // permuted row 0..4095
  int k   = (rem & 255) << 3;
  int gate = (np >> 4) & 3;
  int j    = ((np >> 6) << 4) | (np & 15);
  int n    = (gate << 10) | j;                      // original gate-major row
  const float* src = (k < HD) ? (Wih + ((size_t)(l * 4096 + n) << 10) + k)
                              : (Whh + ((size_t)(l * 4096 + n) << 10) + (k - HD));
  float4 a = reinterpret_cast<const float4*>(src)[0];
  float4 b = reinterpret_cast<const float4*>(src)[1];
  union { u16 s[8]; short8 v; } o;
  o.s[0]=f2bf(a.x); o.s[1]=f2bf(a.y); o.s[2]=f2bf(a.z); o.s[3]=f2bf(a.w);
  o.s[4]=f2bf(b.x); o.s[5]=f2bf(b.y); o.s[6]=f2bf(b.z); o.s[7]=f2bf(b.w);
  *reinterpret_cast<short8*>(W2 + (((size_t)l * 4096 + np) << 11) + k) = o.v;
}

// ---- to_h_W fp32 -> bf16, same [2048][1024] layout
__global__ void pack_thw(const float* __restrict__ thw, u16* __restrict__ dst) {
  int idx = blockIdx.x * 256 + threadIdx.x;        // 262144 threads
  size_t off = (size_t)idx << 3;
  float4 a = reinterpret_cast<const float4*>(thw + off)[0];
  float4 b = reinterpret_cast<const float4*>(thw + off)[1];
  union { u16 s[8]; short8 v; } o;
  o.s[0]=f2bf(a.x); o.s[1]=f2bf(a.y); o.s[2]=f2bf(a.z); o.s[3]=f2bf(a.w);
  o.s[4]=f2bf(b.x); o.s[5]=f2bf(b.y); o.s[6]=f2bf(b.z); o.s[7]=f2bf(b.w);
  *reinterpret_cast<short8*>(dst + off) = o.v;
}

// ---- z->bf16 | x0 = broadcast(init_emb) bf16 | bias2[l][n'] = b_ih+b_hh permuted
__global__ void pack_small(const float* __restrict__ z, const float* __restrict__ emb,
                           const float* __restrict__ bih, const float* __restrict__ bhh,
                           u16* __restrict__ zb, u16* __restrict__ xb,
                           float* __restrict__ bias2) {
  int idx = blockIdx.x * 256 + threadIdx.x;        // 139264 total
  if (idx < 65536) {
    size_t off = (size_t)idx << 3;
    float4 a = reinterpret_cast<const float4*>(z + off)[0];
    float4 b = reinterpret_cast<const float4*>(z + off)[1];
    union { u16 s[8]; short8 v; } o;
    o.s[0]=f2bf(a.x); o.s[1]=f2bf(a.y); o.s[2]=f2bf(a.z); o.s[3]=f2bf(a.w);
    o.s[4]=f2bf(b.x); o.s[5]=f2bf(b.y); o.s[6]=f2bf(b.z); o.s[7]=f2bf(b.w);
    *reinterpret_cast<short8*>(zb + off) = o.v;
  } else if (idx < 131072) {
    size_t off = (size_t)(idx - 65536) << 3;
    int k = (int)(off & 1023);
    float4 a = reinterpret_cast<const float4*>(emb + k)[0];
    float4 b = reinterpret_cast<const float4*>(emb + k)[1];
    union { u16 s[8]; short8 v; } o;
    o.s[0]=f2bf(a.x); o.s[1]=f2bf(a.y); o.s[2]=f2bf(a.z); o.s[3]=f2bf(a.w);
    o.s[4]=f2bf(b.x); o.s[5]=f2bf(b.y); o.s[6]=f2bf(b.z); o.s[7]=f2bf(b.w);
    *reinterpret_cast<short8*>(xb + off) = o.v;
  } else if (idx < 139264) {
    int q = idx - 131072;                          // 0..8191
    int l = q >> 12, np = q & 4095;
    int gate = (np >> 4) & 3;
    int j    = ((np >> 6) << 4) | (np & 15);
    int n    = (gate << 10) | j;
    bias2[(l << 12) + np] = bih[(l << 12) + n] + bhh[(l << 12) + n];
  }
}

// ---- fused GEMM + epilogue.
// C[M=512, N] = A[512, K]bf16 @ W[N, K]bf16^T   (W row-major [N][K], stride K)
// A split: cols [0,1024) from A0, [1024,2048) from A1 (both [512][1024] bf16).
// Tile 64x64, 4 waves each 16 rows x 64 cols -> all 4 gates lane-local.
// 3-buffer LDS pipeline, counted vmcnt (4 load_lds/thread/stage -> 8/4/0),
// XOR chunk-swizzle: LDS dest linear, global source chunk cs = cd ^ (row&7),
// ds_read applies same XOR (involution, rule #21).
// EPI=0: init — h=tanh(acc+bias), c=0 (n<1024 -> layer0 else layer1)
// EPI=1: LSTM cell; EPI=2: cell + y fp32
template<int EPI>
__global__ __launch_bounds__(256, 2)
void lstm_gemm(const u16* __restrict__ A0, const u16* __restrict__ A1,
               const u16* __restrict__ W, const float* __restrict__ bias,
               float* __restrict__ cb0, float* __restrict__ cb1,
               u16* __restrict__ hb0, u16* __restrict__ hb1,
               float* __restrict__ yout, int K)
{
  __shared__ u16 smem[3 * 8192];                  // 3 x (8KB A + 8KB B) = 48 KB
  const int tid  = threadIdx.x;
  const int lane = tid & 63;
  const int wave = tid >> 6;                      // 4 waves: rows wave*16..+15
  const int lr = lane & 15, lk = lane >> 4;
  const int m0 = blockIdx.y * BM;
  const int n0 = blockIdx.x * BN;

  f32x4 acc[4];
  #pragma unroll
  for (int g = 0; g < 4; ++g) acc[g] = (f32x4){0.f, 0.f, 0.f, 0.f};

  auto stage = [&](int buf, int kt) {
    const int k0 = kt * BK;
    u16* Ad = smem + buf * 8192;
    u16* Bd = Ad + 4096;
    const u16* Aptr; int kk;
    if (k0 < 1024) { Aptr = A0; kk = k0; } else { Aptr = A1; kk = k0 - 1024; }
    #pragma unroll
    for (int i = 0; i < 2; ++i) {                 // A: 64 rows x 8 chunks(16B) = 512
      int d = i * 256 + tid;
      int r = d >> 3, cd = d & 7;
      int cs = cd ^ (r & 7);
      const u16* g = Aptr + (((size_t)(m0 + r)) << 10) + kk + cs * 8;
      __builtin_amdgcn_global_load_lds((const __attribute__((address_space(1))) void*)g,
                                       (__attribute__((address_space(3))) void*)(Ad + d * 8),
                                       16, 0, 0);
    }
    #pragma unroll
    for (int i = 0; i < 2; ++i) {                 // B: 64 rows x 8 chunks = 512
      int d = i * 256 + tid;
      int r = d >> 3, cd = d & 7;
      int cs = cd ^ (r & 7);
      const u16* g = W + (size_t)(n0 + r) * K + k0 + cs * 8;
      __builtin_amdgcn_global_load_lds((const __attribute__((address_space(1))) void*)g,
                                       (__attribute__((address_space(3))) void*)(Bd + d * 8),
                                       16, 0, 0);
    }
  };

  const int NT = K / BK;
  stage(0, 0);
  stage(1, 1);

  for (int kt = 0; kt < NT; ++kt) {
    if (kt + 2 < NT) {
      stage((kt + 2) % 3, kt + 2);
      asm volatile("s_waitcnt vmcnt(8)" ::: "memory");   // tile kt's 4 loads done
    } else if (kt + 1 < NT) {
      asm volatile("s_waitcnt vmcnt(4)" ::: "memory");
    } else {
      asm volatile("s_waitcnt vmcnt(0)" ::: "memory");
    }
    __builtin_amdgcn_s_barrier();
    __builtin_amdgcn_sched_barrier(0);            // no LDS reads hoisted above barrier

    const u16* Asb = smem + (kt % 3) * 8192;
    const u16* Bsb = Asb + 4096;
    #pragma unroll
    for (int ks = 0; ks < 2; ++ks) {
      const int ra = wave * 16 + lr;
      const int sw = (ks * 4 + lk) ^ (lr & 7);    // chunk XOR swizzle (r&7 == lr&7)
      short8 a = *reinterpret_cast<const short8*>(Asb + ra * 64 + sw * 8);
      #pragma unroll
      for (int g = 0; g < 4; ++g) {
        const int rb = g * 16 + lr;
        short8 b = *reinterpret_cast<const short8*>(Bsb + rb * 64 + sw * 8);
        acc[g] = __builtin_amdgcn_mfma_f32_16x16x32_bf16(a, b, acc[g], 0, 0, 0);
      }
    }
    asm volatile("s_waitcnt lgkmcnt(0)" ::: "memory");   // all reads of buf done
    __builtin_amdgcn_s_barrier();                        // before next stage overwrites
    __builtin_amdgcn_sched_barrier(0);
  }

  if constexpr (EPI == 0) {
    #pragma unroll
    for (int g = 0; g < 4; ++g) {
      int n = n0 + g * 16 + lr;                   // plain column (no gate permute)
      float bn = bias[n];
      int lsel = n >> 10, j = n & 1023;
      float* cb = lsel ? cb1 : cb0;
      u16*   hb = lsel ? hb1 : hb0;
      #pragma unroll
      for (int i = 0; i < 4; ++i) {
        int r = m0 + wave * 16 + lk * 4 + i;
        size_t idx = ((size_t)r << 10) + j;
        hb[idx] = f2bf(tanhfast(acc[g][i] + bn));
        cb[idx] = 0.f;
      }
    }
  } else {
    float bi = bias[n0 +  0 + lr];
    float bf = bias[n0 + 16 + lr];
    float bg = bias[n0 + 32 + lr];
    float bo = bias[n0 + 48 + lr];
    int j = blockIdx.x * 16 + lr;                 // hidden unit
    #pragma unroll
    for (int i = 0; i < 4; ++i) {
      int r = m0 + wave * 16 + lk * 4 + i;
      size_t idx = ((size_t)r << 10) + j;
      float ig = sigm(acc[0][i] + bi);
      float fg = sigm(acc[1][i] + bf);
      float gg = tanhfast(acc[2][i] + bg);
      float og = sigm(acc[3][i] + bo);
      float cn = fg * cb0[idx] + ig * gg;
      cb0[idx] = cn;
      float hn = og * tanhfast(cn);
      hb0[idx] = f2bf(hn);
      if constexpr (EPI == 2) yout[idx] = hn;
    }
  }
}

extern "C" void kernel_launch(void* const* d_in, const int* in_sizes, int n_in,
                              void* d_out, int out_size, void* d_ws, size_t ws_size,
                              hipStream_t stream) {
  const float* z   = (const float*)d_in[0];
  const float* thw = (const float*)d_in[1];
  const float* thb = (const float*)d_in[2];
  const float* emb = (const float*)d_in[3];
  const float* Wih = (const float*)d_in[4];
  const float* Whh = (const float*)d_in[5];
  const float* bih = (const float*)d_in[6];
  const float* bhh = (const float*)d_in[7];
  float* out = (float*)d_out;

  char* ws = (char*)d_ws;
  size_t off = 0;
  auto carve = [&](size_t bytes) { char* p = ws + off; off += (bytes + 255) & ~(size_t)255; return p; };
  u16* W2     = (u16*)carve((size_t)NL * 4096 * 2048 * 2);   // 33.5 MB, gate-interleaved
  u16* thwb   = (u16*)carve((size_t)2048 * 1024 * 2);        // 4 MB
  u16* zb     = (u16*)carve((size_t)BSZ * HD * 2);
  u16* xb     = (u16*)carve((size_t)BSZ * HD * 2);
  u16* h0b0   = (u16*)carve((size_t)BSZ * HD * 2);
  u16* h0b1   = (u16*)carve((size_t)BSZ * HD * 2);
  u16* h1b0   = (u16*)carve((size_t)BSZ * HD * 2);
  u16* h1b1   = (u16*)carve((size_t)BSZ * HD * 2);
  float* c0   = (float*)carve((size_t)BSZ * HD * 4);
  float* c1   = (float*)carve((size_t)BSZ * HD * 4);
  float* bias2 = (float*)carve((size_t)NL * 4096 * 4);
  if (off > ws_size) return;   // fail loudly rather than corrupt

  u16* h0b[2] = { h0b0, h0b1 };
  u16* h1b[2] = { h1b0, h1b1 };

  pack_w2   <<<8192, 256, 0, stream>>>(Wih, Whh, W2);
  pack_thw  <<<1024, 256, 0, stream>>>(thw, thwb);
  pack_small<<< 544, 256, 0, stream>>>(z, emb, bih, bhh, zb, xb, bias2);

  // h0 init: tanh(z @ to_h_W^T + to_h_b); also zeroes c0/c1
  lstm_gemm<0><<<dim3(32, 8), 256, 0, stream>>>(zb, zb, thwb, thb,
                                                c0, c1, h0b[0], h1b[0], nullptr, 1024);

  for (int t = 0; t < TSTEPS; ++t) {
    const u16* xs = (t == 0) ? xb : h1b[t & 1];
    // layer 0: gates = [x | h0_old] @ W2[0]^T; writes h0_new (ping-pong), c0
    lstm_gemm<1><<<dim3(64, 8), 256, 0, stream>>>(
        xs, h0b[t & 1], W2, bias2,
        c0, nullptr, h0b[(t + 1) & 1], nullptr, nullptr, 2048);
    // layer 1: gates = [h0_new | h1_old] @ W2[1]^T; writes h1_new, c1, y_t
    lstm_gemm<2><<<dim3(64, 8), 256, 0, stream>>>(
        h0b[(t + 1) & 1], h1b[t & 1], W2 + (size_t)4096 * 2048, bias2 + 4096,
        c1, nullptr, h1b[(t + 1) & 1], nullptr, out + (size_t)t * BSZ * HD, 2048);
  }
}